// Round 2
// baseline (772.717 us; speedup 1.0000x reference)
//
#include <hip/hip_runtime.h>

// GNN: 4x GraphSAGE(mean) + skip Linear + BN(1-3) + ReLU(1-3), fp32.
// N=50000 nodes, E=800000 edges, dims 128->256->128->64->40.
//
// Fusions:
//  - h@Wr + h@Ws  => h@(Wr+Ws) (B-tile summed on load)
//  - BN folded to per-column affine (a,b); applied at next layer's reads.
//    agg affine applied in aggregate kernel (gated on deg>0 for exactness).
//  - GEMM epilogue computes BN column sums/sumsq (biased var) via LDS tree +
//    global atomics; tiny kernel converts to (a,b).
//  - sums zeroing folded into aggregate (block n==0) to drop 3 memsets.
// Aggregation: per-call CSR build (count -> 3-phase scan -> fill), then
// pull-mode gather (block per node, thread per column), index loop unrolled
// x4 for memory-level parallelism. No float atomics anywhere.

static constexpr int NN = 50000;
static constexpr int NE = 800000;

static constexpr int BM = 64, BN = 64, BK = 32;
static constexpr int LDA = BM + 4;  // 68: k-major A tile, 16B-aligned float4 rows
static constexpr int LDB = BN + 4;  // 68

__global__ void count_deg(const int* __restrict__ dst, int* __restrict__ cnt, int E) {
  int e = blockIdx.x * blockDim.x + threadIdx.x;
  if (e < E) atomicAdd(&cnt[dst[e]], 1);
}

// Phase 1: per-1024-block exclusive scan + block totals.
__global__ __launch_bounds__(1024) void scan_block(const int* __restrict__ cnt,
                                                   int* __restrict__ excl,
                                                   int* __restrict__ btot, int n) {
  __shared__ int lds[1024];
  int i = blockIdx.x * 1024 + threadIdx.x;
  int v = (i < n) ? cnt[i] : 0;
  lds[threadIdx.x] = v;
  __syncthreads();
#pragma unroll
  for (int off = 1; off < 1024; off <<= 1) {
    int t = 0;
    if ((int)threadIdx.x >= off) t = lds[threadIdx.x - off];
    __syncthreads();
    lds[threadIdx.x] += t;
    __syncthreads();
  }
  if (i < n) excl[i] = lds[threadIdx.x] - v;
  if (threadIdx.x == 1023) btot[blockIdx.x] = lds[1023];
}

// Phase 2: exclusive scan of block totals (nb <= 64) in one wave.
__global__ void scan_tops(int* __restrict__ btot, int nb) {
  int t = threadIdx.x;
  int v = (t < nb) ? btot[t] : 0;
  int own = v;
#pragma unroll
  for (int off = 1; off < 64; off <<= 1) {
    int u = __shfl_up(v, off);
    if (t >= off) v += u;
  }
  if (t < nb) btot[t] = v - own;
}

// Phase 3: add block base -> final offs; init cursor copy; 1/max(deg,1).
__global__ void finalize_csr(int* __restrict__ offs, const int* __restrict__ btot,
                             const int* __restrict__ cnt, int* __restrict__ cursor,
                             float* __restrict__ inv, int n) {
  int i = blockIdx.x * blockDim.x + threadIdx.x;
  if (i < n) {
    int o = offs[i] + btot[i >> 10];
    offs[i] = o;
    cursor[i] = o;
    int c = cnt[i];
    inv[i] = 1.0f / (float)(c > 0 ? c : 1);
  }
}

__global__ void fill_adj(const int* __restrict__ src, const int* __restrict__ dst,
                         int* __restrict__ cursor, int* __restrict__ adj, int E) {
  int e = blockIdx.x * blockDim.x + threadIdx.x;
  if (e < E) {
    int p = atomicAdd(&cursor[dst[e]], 1);
    adj[p] = src[e];
  }
}

// block = D threads, grid = N. Pull-aggregate mean of h over incoming nbrs.
// If ab != nullptr, applies y = a*mean + b (prev layer's BN), exact for deg==0.
// Block 0 also zeroes sums[0..511] for the following GEMM's BN stats.
__global__ void aggregate(const float* __restrict__ h, const int* __restrict__ adj,
                          const int* __restrict__ offs, const int* __restrict__ cnt,
                          const float* __restrict__ inv, const float* __restrict__ ab,
                          float* __restrict__ agg, float* __restrict__ sums, int D) {
  int n = blockIdx.x;
  int t = threadIdx.x;
  if (n == 0 && sums) {
    for (int j = t; j < 512; j += blockDim.x) sums[j] = 0.f;
  }
  int off = offs[n];
  int deg = cnt[n];
  const float* __restrict__ hp = h + t;
  float s = 0.f;
  int i = 0;
  for (; i + 4 <= deg; i += 4) {
    int s0 = adj[off + i + 0];
    int s1 = adj[off + i + 1];
    int s2 = adj[off + i + 2];
    int s3 = adj[off + i + 3];
    float v0 = hp[(size_t)s0 * D];
    float v1 = hp[(size_t)s1 * D];
    float v2 = hp[(size_t)s2 * D];
    float v3 = hp[(size_t)s3 * D];
    s += (v0 + v1) + (v2 + v3);
  }
  for (; i < deg; ++i) s += hp[(size_t)adj[off + i] * D];
  float m = s * inv[n];
  if (ab) m = (deg > 0) ? fmaf(ab[t], m, ab[D + t]) : 0.f;
  agg[(size_t)n * D + t] = m;
}

// Out[r][c] = sum_k agg[r][k]*Wl[k][c] + sum_k haff[r][k]*(Wr+Ws)[k][c] + bl[c]+bs[c]
// haff = AFFINE ? a*h+b : h (a,b from prev BN). Optional ReLU; optional column
// sum/sumsq accumulation for this layer's BN.
template <int RELU, int STATS, int AFFINE>
__global__ __launch_bounds__(256) void gemm_fused(
    const float* __restrict__ Agg, const float* __restrict__ H,
    const float* __restrict__ Wl, const float* __restrict__ Wr,
    const float* __restrict__ Wsk, const float* __restrict__ bl,
    const float* __restrict__ bs, const float* __restrict__ ab,
    float* __restrict__ Out, float* __restrict__ sums, int N, int K, int M) {
  __shared__ float As[BK][LDA];
  __shared__ float Bs[BK][LDB];
  const int tid = threadIdx.x;
  const int tx = tid & 15, ty = tid >> 4;
  const int row0 = blockIdx.x * BM, col0 = blockIdx.y * BN;

  float acc[4][4] = {};

  const int alr = tid >> 3;        // 0..31 (+32)
  const int alc = (tid & 7) * 4;   // k offset in tile
  const int bkr = tid >> 4;        // 0..15 (+16)
  const int bcc = (tid & 15) * 4;  // col offset in tile

  for (int phase = 0; phase < 2; ++phase) {
    const float* __restrict__ A = phase ? H : Agg;
    for (int k0 = 0; k0 < K; k0 += BK) {
#pragma unroll
      for (int hh = 0; hh < 2; ++hh) {
        int r = row0 + alr + hh * 32;
        float4 av = make_float4(0.f, 0.f, 0.f, 0.f);
        if (r < N) av = *(const float4*)&A[(size_t)r * K + k0 + alc];
        if (AFFINE && phase == 1) {
          float4 aa = *(const float4*)&ab[k0 + alc];
          float4 bb = *(const float4*)&ab[K + k0 + alc];
          av.x = fmaf(aa.x, av.x, bb.x);
          av.y = fmaf(aa.y, av.y, bb.y);
          av.z = fmaf(aa.z, av.z, bb.z);
          av.w = fmaf(aa.w, av.w, bb.w);
        }
        As[alc + 0][alr + hh * 32] = av.x;
        As[alc + 1][alr + hh * 32] = av.y;
        As[alc + 2][alr + hh * 32] = av.z;
        As[alc + 3][alr + hh * 32] = av.w;
      }
#pragma unroll
      for (int hh = 0; hh < 2; ++hh) {
        int kr = k0 + bkr + hh * 16;
        int c = col0 + bcc;
        float4 bv = make_float4(0.f, 0.f, 0.f, 0.f);
        if (c < M) {  // M % 4 == 0, so c < M implies c+3 < M
          if (phase == 0) {
            bv = *(const float4*)&Wl[(size_t)kr * M + c];
          } else {
            float4 b1 = *(const float4*)&Wr[(size_t)kr * M + c];
            float4 b2 = *(const float4*)&Wsk[(size_t)kr * M + c];
            bv.x = b1.x + b2.x; bv.y = b1.y + b2.y;
            bv.z = b1.z + b2.z; bv.w = b1.w + b2.w;
          }
        }
        *(float4*)&Bs[bkr + hh * 16][bcc] = bv;
      }
      __syncthreads();
#pragma unroll
      for (int kk = 0; kk < BK; ++kk) {
        float a4[4], b4[4];
        *(float4*)a4 = *(const float4*)&As[kk][ty * 4];
        *(float4*)b4 = *(const float4*)&Bs[kk][tx * 4];
#pragma unroll
        for (int i = 0; i < 4; ++i)
#pragma unroll
          for (int j = 0; j < 4; ++j) acc[i][j] = fmaf(a4[i], b4[j], acc[i][j]);
      }
      __syncthreads();
    }
  }

  float bias[4];
#pragma unroll
  for (int j = 0; j < 4; ++j) {
    int c = col0 + tx * 4 + j;
    bias[j] = (c < M) ? (bl[c] + bs[c]) : 0.f;
  }

  float cs[4] = {0.f, 0.f, 0.f, 0.f}, cq[4] = {0.f, 0.f, 0.f, 0.f};
#pragma unroll
  for (int i = 0; i < 4; ++i) {
    int r = row0 + ty * 4 + i;
    if (r >= N) continue;
    float v[4];
#pragma unroll
    for (int j = 0; j < 4; ++j) {
      float t = acc[i][j] + bias[j];
      if (RELU) t = fmaxf(t, 0.f);
      v[j] = t;
      if (STATS) {
        cs[j] += t;
        cq[j] += t * t;
      }
    }
    if (col0 + tx * 4 < M)
      *(float4*)&Out[(size_t)r * M + col0 + tx * 4] =
          make_float4(v[0], v[1], v[2], v[3]);
  }

  if (STATS) {
    // reuse As/Bs as 16x64 partial arrays (main loop ended with a barrier)
    float* part1 = &As[0][0];
    float* part2 = &Bs[0][0];
#pragma unroll
    for (int j = 0; j < 4; ++j) {
      part1[ty * 64 + tx * 4 + j] = cs[j];
      part2[ty * 64 + tx * 4 + j] = cq[j];
    }
    __syncthreads();
    if (tid < 64) {
      float s1v = 0.f, s2v = 0.f;
#pragma unroll
      for (int t2 = 0; t2 < 16; ++t2) {
        s1v += part1[t2 * 64 + tid];
        s2v += part2[t2 * 64 + tid];
      }
      int c = col0 + tid;
      if (c < M) {
        atomicAdd(&sums[c], s1v);
        atomicAdd(&sums[M + c], s2v);
      }
    }
  }
}

__global__ void bn_affine(const float* __restrict__ sums, const float* __restrict__ g,
                          const float* __restrict__ be, float* __restrict__ ab,
                          int M, float invN) {
  int j = threadIdx.x;
  if (j < M) {
    float mu = sums[j] * invN;
    float var = fmaf(-mu, mu, sums[M + j] * invN);
    float a = g[j] / sqrtf(var + 1e-5f);
    ab[j] = a;
    ab[M + j] = fmaf(-mu, a, be[j]);
  }
}

extern "C" void kernel_launch(void* const* d_in, const int* in_sizes, int n_in,
                              void* d_out, int out_size, void* d_ws, size_t ws_size,
                              hipStream_t stream) {
  const int N = NN, E = NE;
  const float* x = (const float*)d_in[0];
  const int* ei = (const int*)d_in[1];
  const int* srcs = ei;       // edge_index[0]
  const int* dsts = ei + E;   // edge_index[1]

  const float* Wl1 = (const float*)d_in[2];
  const float* bl1 = (const float*)d_in[3];
  const float* Wr1 = (const float*)d_in[4];
  const float* Ws1 = (const float*)d_in[5];
  const float* bs1 = (const float*)d_in[6];
  const float* g1  = (const float*)d_in[7];
  const float* be1 = (const float*)d_in[8];
  const float* Wl2 = (const float*)d_in[9];
  const float* bl2 = (const float*)d_in[10];
  const float* Wr2 = (const float*)d_in[11];
  const float* Ws2 = (const float*)d_in[12];
  const float* bs2 = (const float*)d_in[13];
  const float* g2  = (const float*)d_in[14];
  const float* be2 = (const float*)d_in[15];
  const float* Wl3 = (const float*)d_in[16];
  const float* bl3 = (const float*)d_in[17];
  const float* Wr3 = (const float*)d_in[18];
  const float* Ws3 = (const float*)d_in[19];
  const float* bs3 = (const float*)d_in[20];
  const float* g3  = (const float*)d_in[21];
  const float* be3 = (const float*)d_in[22];
  const float* Wl4 = (const float*)d_in[23];
  const float* bl4 = (const float*)d_in[24];
  const float* Wr4 = (const float*)d_in[25];
  const float* Ws4 = (const float*)d_in[26];
  const float* bs4 = (const float*)d_in[27];

  // workspace layout (~132 MB)
  float* ws = (float*)d_ws;
  float* hA = ws;                          // N*256
  float* hB = hA + (size_t)N * 256;        // N*128
  float* agg = hB + (size_t)N * 128;       // N*256
  float* sums = agg + (size_t)N * 256;     // 512
  float* ab = sums + 512;                  // 512
  float* invc = ab + 512;                  // N
  int* cnt = (int*)(invc + N);             // N
  int* offs = cnt + N;                     // N
  int* cursor = offs + N;                  // N
  int* btot = cursor + N;                  // 64
  int* adj = btot + 64;                    // E

  hipMemsetAsync(cnt, 0, sizeof(int) * N, stream);
  int eb = (E + 255) / 256;
  int nb = (N + 1023) / 1024;  // 49
  count_deg<<<eb, 256, 0, stream>>>(dsts, cnt, E);
  scan_block<<<nb, 1024, 0, stream>>>(cnt, offs, btot, N);
  scan_tops<<<1, 64, 0, stream>>>(btot, nb);
  finalize_csr<<<(N + 255) / 256, 256, 0, stream>>>(offs, btot, cnt, cursor, invc, N);
  fill_adj<<<eb, 256, 0, stream>>>(srcs, dsts, cursor, adj, E);

  const int MB = (N + BM - 1) / BM;  // 782
  const float invN = 1.0f / (float)N;

  // Layer 1: x(128) -> hA(256), relu + stats, no input affine
  aggregate<<<N, 128, 0, stream>>>(x, adj, offs, cnt, invc, nullptr, agg, sums, 128);
  gemm_fused<1, 1, 0><<<dim3(MB, 4), 256, 0, stream>>>(
      agg, x, Wl1, Wr1, Ws1, bl1, bs1, nullptr, hA, sums, N, 128, 256);
  bn_affine<<<1, 256, 0, stream>>>(sums, g1, be1, ab, 256, invN);

  // Layer 2: hA(256) -> hB(128), input affine from BN1
  aggregate<<<N, 256, 0, stream>>>(hA, adj, offs, cnt, invc, ab, agg, sums, 256);
  gemm_fused<1, 1, 1><<<dim3(MB, 2), 256, 0, stream>>>(
      agg, hA, Wl2, Wr2, Ws2, bl2, bs2, ab, hB, sums, N, 256, 128);
  bn_affine<<<1, 128, 0, stream>>>(sums, g2, be2, ab, 128, invN);

  // Layer 3: hB(128) -> hA(64), input affine from BN2
  aggregate<<<N, 128, 0, stream>>>(hB, adj, offs, cnt, invc, ab, agg, sums, 128);
  gemm_fused<1, 1, 1><<<dim3(MB, 1), 256, 0, stream>>>(
      agg, hB, Wl3, Wr3, Ws3, bl3, bs3, ab, hA, sums, N, 128, 64);
  bn_affine<<<1, 64, 0, stream>>>(sums, g3, be3, ab, 64, invN);

  // Layer 4: hA(64) -> d_out(40), no relu/stats, input affine from BN3
  aggregate<<<N, 64, 0, stream>>>(hA, adj, offs, cnt, invc, ab, agg, nullptr, 64);
  gemm_fused<0, 0, 1><<<dim3(MB, 1), 256, 0, stream>>>(
      agg, hA, Wl4, Wr4, Ws4, bl4, bs4, ab, (float*)d_out, nullptr, N, 64, 40);
}

// Round 3
// 764.924 us; speedup vs baseline: 1.0102x; 1.0102x over previous
//
#include <hip/hip_runtime.h>

// GNN: 4x GraphSAGE(mean) + skip Linear + BN(1-3) + ReLU(1-3), fp32.
// N=50000 nodes, E=800000 edges, dims 128->256->128->64->40.
//
// Structure (round 2):
//  - L1 (128->256): aggregate x first (gather on 128-dim), then ONE GEMM with
//    A = [agg | x] stacked along K, B = [Wl1 ; Wr1+Ws1], fused bias+relu+stats.
//  - L2-4 (dim shrinks): GEMM FIRST (Z = h_aff @ [Wl | Wr+Ws], width 2*dout),
//    then "combine" kernel: y = mean_nbrs(Zl[src]) + Zr + bias (+relu+stats).
//    Aggregation commutes with the linear map; gather traffic drops 38%.
//  - BN folded to per-column affine (a,b), applied on GEMM A-loads; deg==0 is
//    exact for free (mean of nothing = 0 both sides).
//  - bn_affine self-zeroes sums for the next layer's stats.
// GEMM: 128x128 block, BK=16, 256 thr, 8x8 microtile (split-halves layout so
// LDS reads are <=2-way bank-aliased = free).

static constexpr int NN = 50000;
static constexpr int NE = 800000;

static constexpr int BM = 128, BN = 128, BK = 16;
static constexpr int LDT = BM + 4;  // 132

__global__ void count_deg(const int* __restrict__ dst, int* __restrict__ cnt, int E) {
  int e = blockIdx.x * blockDim.x + threadIdx.x;
  if (e < E) atomicAdd(&cnt[dst[e]], 1);
}

__global__ __launch_bounds__(1024) void scan_block(const int* __restrict__ cnt,
                                                   int* __restrict__ excl,
                                                   int* __restrict__ btot, int n) {
  __shared__ int lds[1024];
  int i = blockIdx.x * 1024 + threadIdx.x;
  int v = (i < n) ? cnt[i] : 0;
  lds[threadIdx.x] = v;
  __syncthreads();
#pragma unroll
  for (int off = 1; off < 1024; off <<= 1) {
    int t = 0;
    if ((int)threadIdx.x >= off) t = lds[threadIdx.x - off];
    __syncthreads();
    lds[threadIdx.x] += t;
    __syncthreads();
  }
  if (i < n) excl[i] = lds[threadIdx.x] - v;
  if (threadIdx.x == 1023) btot[blockIdx.x] = lds[1023];
}

__global__ void scan_tops(int* __restrict__ btot, int nb) {
  int t = threadIdx.x;
  int v = (t < nb) ? btot[t] : 0;
  int own = v;
#pragma unroll
  for (int off = 1; off < 64; off <<= 1) {
    int u = __shfl_up(v, off);
    if (t >= off) v += u;
  }
  if (t < nb) btot[t] = v - own;
}

__global__ void finalize_csr(int* __restrict__ offs, const int* __restrict__ btot,
                             const int* __restrict__ cnt, int* __restrict__ cursor,
                             float* __restrict__ inv, int n) {
  int i = blockIdx.x * blockDim.x + threadIdx.x;
  if (i < n) {
    int o = offs[i] + btot[i >> 10];
    offs[i] = o;
    cursor[i] = o;
    int c = cnt[i];
    inv[i] = 1.0f / (float)(c > 0 ? c : 1);
  }
}

__global__ void fill_adj(const int* __restrict__ src, const int* __restrict__ dst,
                         int* __restrict__ cursor, int* __restrict__ adj, int E) {
  int e = blockIdx.x * blockDim.x + threadIdx.x;
  if (e < E) {
    int p = atomicAdd(&cursor[dst[e]], 1);
    adj[p] = src[e];
  }
}

// L1 pre-aggregation of x (D=128). Block 0 zeroes sums for L1 stats.
__global__ void aggregate1(const float* __restrict__ h, const int* __restrict__ adj,
                           const int* __restrict__ offs, const int* __restrict__ cnt,
                           const float* __restrict__ inv, float* __restrict__ agg,
                           float* __restrict__ sums) {
  const int D = 128;
  int n = blockIdx.x;
  int t = threadIdx.x;
  if (n == 0) {
    for (int j = t; j < 512; j += D) sums[j] = 0.f;
  }
  int off = offs[n];
  int deg = cnt[n];
  const float* __restrict__ hp = h + t;
  float s = 0.f;
  int i = 0;
  for (; i + 4 <= deg; i += 4) {
    int s0 = adj[off + i + 0];
    int s1 = adj[off + i + 1];
    int s2 = adj[off + i + 2];
    int s3 = adj[off + i + 3];
    float v0 = hp[(size_t)s0 * D];
    float v1 = hp[(size_t)s1 * D];
    float v2 = hp[(size_t)s2 * D];
    float v3 = hp[(size_t)s3 * D];
    s += (v0 + v1) + (v2 + v3);
  }
  for (; i < deg; ++i) s += hp[(size_t)adj[off + i] * D];
  agg[(size_t)n * D + t] = s * inv[n];
}

// C[N x Mp] = A @ B.
// TWO_A (L1): A = [A1 | A2] along K (K1,K2), B = [Wl ; Wr+Ws] along K, Mp=M.
// else:       A = A1 (affine a*h+b if AFFINE), B = [Wl | Wr+Ws] cols, Mp=2M.
// EPI: += (bl+bs), relu, write; column sum/sumsq into sums (L1).
template <int TWO_A, int AFFINE, int EPI>
__global__ __launch_bounds__(256) void gemm_big(
    const float* __restrict__ A1, const float* __restrict__ A2,
    const float* __restrict__ Wl, const float* __restrict__ Wr,
    const float* __restrict__ Wsk, const float* __restrict__ bl,
    const float* __restrict__ bs, const float* __restrict__ ab,
    float* __restrict__ Out, float* __restrict__ sums,
    int N, int K1, int K2, int M) {
  __shared__ float As[BK][LDT];
  __shared__ float Bs[BK][LDT];
  const int tid = threadIdx.x;
  const int tx = tid & 15, ty = tid >> 4;
  const int row0 = blockIdx.x * BM, col0 = blockIdx.y * BN;
  const int Mp = TWO_A ? M : 2 * M;
  const int Ktot = K1 + K2;

  float acc[2][2][4][4] = {};

  for (int k0 = 0; k0 < Ktot; k0 += BK) {
    const float* __restrict__ Asrc = A1;
    int kl = k0, SA = K1;
    if (TWO_A && k0 >= K1) { Asrc = A2; kl = k0 - K1; SA = K2; }
#pragma unroll
    for (int u = 0; u < 2; ++u) {
      int i4 = tid * 2 + u;
      int r = i4 >> 2, kc = (i4 & 3) * 4;
      float4 av = make_float4(0.f, 0.f, 0.f, 0.f);
      if (row0 + r < N) av = *(const float4*)&Asrc[(size_t)(row0 + r) * SA + kl + kc];
      if (AFFINE) {
        float4 aa = *(const float4*)&ab[kl + kc];
        float4 bb = *(const float4*)&ab[K1 + kl + kc];
        av.x = fmaf(aa.x, av.x, bb.x);
        av.y = fmaf(aa.y, av.y, bb.y);
        av.z = fmaf(aa.z, av.z, bb.z);
        av.w = fmaf(aa.w, av.w, bb.w);
      }
      As[kc + 0][r] = av.x;
      As[kc + 1][r] = av.y;
      As[kc + 2][r] = av.z;
      As[kc + 3][r] = av.w;
    }
#pragma unroll
    for (int u = 0; u < 2; ++u) {
      int i4 = tid * 2 + u;
      int k = i4 >> 5, c4 = (i4 & 31) * 4;
      int kg = k0 + k;
      int c = col0 + c4;
      float4 bv = make_float4(0.f, 0.f, 0.f, 0.f);
      if (c < Mp) {
        if (TWO_A) {
          if (kg < K1) {
            bv = *(const float4*)&Wl[(size_t)kg * M + c];
          } else {
            float4 b1 = *(const float4*)&Wr[(size_t)(kg - K1) * M + c];
            float4 b2 = *(const float4*)&Wsk[(size_t)(kg - K1) * M + c];
            bv.x = b1.x + b2.x; bv.y = b1.y + b2.y;
            bv.z = b1.z + b2.z; bv.w = b1.w + b2.w;
          }
        } else {
          if (c < M) {
            bv = *(const float4*)&Wl[(size_t)kg * M + c];
          } else {
            float4 b1 = *(const float4*)&Wr[(size_t)kg * M + (c - M)];
            float4 b2 = *(const float4*)&Wsk[(size_t)kg * M + (c - M)];
            bv.x = b1.x + b2.x; bv.y = b1.y + b2.y;
            bv.z = b1.z + b2.z; bv.w = b1.w + b2.w;
          }
        }
      }
      *(float4*)&Bs[k][c4] = bv;
    }
    __syncthreads();
#pragma unroll
    for (int kk = 0; kk < BK; ++kk) {
      float a_[2][4], b_[2][4];
      *(float4*)a_[0] = *(const float4*)&As[kk][ty * 4];
      *(float4*)a_[1] = *(const float4*)&As[kk][64 + ty * 4];
      *(float4*)b_[0] = *(const float4*)&Bs[kk][tx * 4];
      *(float4*)b_[1] = *(const float4*)&Bs[kk][64 + tx * 4];
#pragma unroll
      for (int rh = 0; rh < 2; ++rh)
#pragma unroll
        for (int i = 0; i < 4; ++i)
#pragma unroll
          for (int ch = 0; ch < 2; ++ch)
#pragma unroll
            for (int j = 0; j < 4; ++j)
              acc[rh][ch][i][j] = fmaf(a_[rh][i], b_[ch][j], acc[rh][ch][i][j]);
    }
    __syncthreads();
  }

  if (EPI) {
    float bias[2][4];
    float cs[2][4] = {}, cq[2][4] = {};
#pragma unroll
    for (int ch = 0; ch < 2; ++ch)
#pragma unroll
      for (int j = 0; j < 4; ++j) {
        int c = col0 + ch * 64 + tx * 4 + j;
        bias[ch][j] = (c < Mp) ? (bl[c] + bs[c]) : 0.f;
      }
#pragma unroll
    for (int rh = 0; rh < 2; ++rh)
#pragma unroll
      for (int i = 0; i < 4; ++i) {
        int r = row0 + rh * 64 + ty * 4 + i;
        if (r >= N) continue;
#pragma unroll
        for (int ch = 0; ch < 2; ++ch) {
          int cst = col0 + ch * 64 + tx * 4;
          float v[4];
#pragma unroll
          for (int j = 0; j < 4; ++j) {
            float t = acc[rh][ch][i][j] + bias[ch][j];
            t = fmaxf(t, 0.f);
            v[j] = t;
            cs[ch][j] += t;
            cq[ch][j] += t * t;
          }
          if (cst < Mp)
            *(float4*)&Out[(size_t)r * Mp + cst] = make_float4(v[0], v[1], v[2], v[3]);
        }
      }
    // column-stat reduce: 16 ty-groups x 128 cols in LDS, then atomics.
    float* p1 = &As[0][0];
    float* p2 = &Bs[0][0];
#pragma unroll
    for (int ch = 0; ch < 2; ++ch)
#pragma unroll
      for (int j = 0; j < 4; ++j) {
        int cl = ch * 64 + tx * 4 + j;
        p1[ty * 128 + cl] = cs[ch][j];
        p2[ty * 128 + cl] = cq[ch][j];
      }
    __syncthreads();
    if (tid < 128) {
      float s1 = 0.f, s2 = 0.f;
#pragma unroll
      for (int t2 = 0; t2 < 16; ++t2) {
        s1 += p1[t2 * 128 + tid];
        s2 += p2[t2 * 128 + tid];
      }
      int c = col0 + tid;
      if (c < Mp) {
        atomicAdd(&sums[c], s1);
        atomicAdd(&sums[Mp + c], s2);
      }
    }
  } else {
#pragma unroll
    for (int rh = 0; rh < 2; ++rh)
#pragma unroll
      for (int i = 0; i < 4; ++i) {
        int r = row0 + rh * 64 + ty * 4 + i;
        if (r >= N) continue;
#pragma unroll
        for (int ch = 0; ch < 2; ++ch) {
          int cst = col0 + ch * 64 + tx * 4;
          if (cst < Mp)
            *(float4*)&Out[(size_t)r * Mp + cst] =
                make_float4(acc[rh][ch][i][0], acc[rh][ch][i][1],
                            acc[rh][ch][i][2], acc[rh][ch][i][3]);
        }
      }
  }
}

// y[n][c] = mean_nbrs(Zl[src][c]) + Zr[n][c] + bl[c]+bs[c]; relu/stats opt.
// Z rows are [Zl(M) | Zr(M)], stride 2M. DPAD = M padded to wave multiple.
template <int DPAD, int LOGD, int M, int RELU, int STATS>
__global__ __launch_bounds__(256) void combine(
    const float* __restrict__ Z, const int* __restrict__ adj,
    const int* __restrict__ offs, const int* __restrict__ cnt,
    const float* __restrict__ inv, const float* __restrict__ bl,
    const float* __restrict__ bs, float* __restrict__ out,
    float* __restrict__ sums, int N) {
  constexpr int S = 256 / DPAD;
  constexpr int Mp = 2 * M;
  const int tid = threadIdx.x;
  const int c = tid & (DPAD - 1);
  const int sub = tid >> LOGD;
  const bool act = (c < M);
  const float bias = act ? (bl[c] + bs[c]) : 0.f;
  float cs = 0.f, cq = 0.f;
  const float* __restrict__ Zc = Z + c;
  for (int n = blockIdx.x * S + sub; n < N; n += gridDim.x * S) {
    if (act) {
      int off = offs[n], deg = cnt[n];
      float s = 0.f;
      int i = 0;
      for (; i + 4 <= deg; i += 4) {
        int s0 = adj[off + i + 0];
        int s1 = adj[off + i + 1];
        int s2 = adj[off + i + 2];
        int s3 = adj[off + i + 3];
        float v0 = Zc[(size_t)s0 * Mp];
        float v1 = Zc[(size_t)s1 * Mp];
        float v2 = Zc[(size_t)s2 * Mp];
        float v3 = Zc[(size_t)s3 * Mp];
        s += (v0 + v1) + (v2 + v3);
      }
      for (; i < deg; ++i) s += Zc[(size_t)adj[off + i] * Mp];
      float y = fmaf(s, inv[n], Z[(size_t)n * Mp + M + c] + bias);
      if (RELU) y = fmaxf(y, 0.f);
      out[(size_t)n * M + c] = y;
      if (STATS) { cs += y; cq += y * y; }
    }
  }
  if (STATS) {
    __shared__ float red[512];
    red[tid] = cs;
    red[256 + tid] = cq;
    __syncthreads();
    if (sub == 0 && act) {
#pragma unroll
      for (int s2 = 1; s2 < S; ++s2) {
        cs += red[s2 * DPAD + c];
        cq += red[256 + s2 * DPAD + c];
      }
      atomicAdd(&sums[c], cs);
      atomicAdd(&sums[M + c], cq);
    }
  }
}

__global__ void bn_affine(float* __restrict__ sums, const float* __restrict__ g,
                          const float* __restrict__ be, float* __restrict__ ab,
                          int M, float invN) {
  int j = threadIdx.x;
  if (j < M) {
    float s1 = sums[j], s2 = sums[M + j];
    float mu = s1 * invN;
    float var = fmaf(-mu, mu, s2 * invN);
    float a = g[j] / sqrtf(var + 1e-5f);
    ab[j] = a;
    ab[M + j] = fmaf(-mu, a, be[j]);
    sums[j] = 0.f;       // ready for next layer's stats
    sums[M + j] = 0.f;
  }
}

extern "C" void kernel_launch(void* const* d_in, const int* in_sizes, int n_in,
                              void* d_out, int out_size, void* d_ws, size_t ws_size,
                              hipStream_t stream) {
  const int N = NN, E = NE;
  const float* x = (const float*)d_in[0];
  const int* ei = (const int*)d_in[1];
  const int* srcs = ei;
  const int* dsts = ei + E;

  const float* Wl1 = (const float*)d_in[2];
  const float* bl1 = (const float*)d_in[3];
  const float* Wr1 = (const float*)d_in[4];
  const float* Ws1 = (const float*)d_in[5];
  const float* bs1 = (const float*)d_in[6];
  const float* g1  = (const float*)d_in[7];
  const float* be1 = (const float*)d_in[8];
  const float* Wl2 = (const float*)d_in[9];
  const float* bl2 = (const float*)d_in[10];
  const float* Wr2 = (const float*)d_in[11];
  const float* Ws2 = (const float*)d_in[12];
  const float* bs2 = (const float*)d_in[13];
  const float* g2  = (const float*)d_in[14];
  const float* be2 = (const float*)d_in[15];
  const float* Wl3 = (const float*)d_in[16];
  const float* bl3 = (const float*)d_in[17];
  const float* Wr3 = (const float*)d_in[18];
  const float* Ws3 = (const float*)d_in[19];
  const float* bs3 = (const float*)d_in[20];
  const float* g3  = (const float*)d_in[21];
  const float* be3 = (const float*)d_in[22];
  const float* Wl4 = (const float*)d_in[23];
  const float* bl4 = (const float*)d_in[24];
  const float* Wr4 = (const float*)d_in[25];
  const float* Ws4 = (const float*)d_in[26];
  const float* bs4 = (const float*)d_in[27];

  // workspace (~132 MB)
  float* ws = (float*)d_ws;
  float* Zbuf = ws;                            // N*256 (L1: agg uses N*128)
  float* hA   = Zbuf + (size_t)N * 256;        // N*256
  float* hB   = hA + (size_t)N * 256;          // N*128 (hC aliases it)
  float* sums = hB + (size_t)N * 128;          // 512
  float* ab   = sums + 512;                    // 512
  float* invc = ab + 512;                      // N
  int* cnt    = (int*)(invc + N);              // N
  int* offs   = cnt + N;                       // N
  int* cursor = offs + N;                      // N
  int* btot   = cursor + N;                    // 64
  int* adj    = btot + 64;                     // E
  float* hC = hB;

  hipMemsetAsync(cnt, 0, sizeof(int) * N, stream);
  int eb = (E + 255) / 256;
  int nb = (N + 1023) / 1024;  // 49
  count_deg<<<eb, 256, 0, stream>>>(dsts, cnt, E);
  scan_block<<<nb, 1024, 0, stream>>>(cnt, offs, btot, N);
  scan_tops<<<1, 64, 0, stream>>>(btot, nb);
  finalize_csr<<<(N + 255) / 256, 256, 0, stream>>>(offs, btot, cnt, cursor, invc, N);
  fill_adj<<<eb, 256, 0, stream>>>(srcs, dsts, cursor, adj, E);

  const int RB = (N + BM - 1) / BM;  // 391
  const float invN = 1.0f / (float)N;
  float* agg = Zbuf;

  // L1: aggregate x, then [agg|x] @ [Wl1 ; Wr1+Ws1] + bias, relu, stats -> hA
  aggregate1<<<N, 128, 0, stream>>>(x, adj, offs, cnt, invc, agg, sums);
  gemm_big<1, 0, 1><<<dim3(RB, 2), 256, 0, stream>>>(
      agg, x, Wl1, Wr1, Ws1, bl1, bs1, nullptr, hA, sums, N, 128, 128, 256);
  bn_affine<<<1, 256, 0, stream>>>(sums, g1, be1, ab, 256, invN);

  // L2: Z = bn1(hA) @ [Wl2 | Wr2+Ws2]; combine -> hB (relu+stats)
  gemm_big<0, 1, 0><<<dim3(RB, 2), 256, 0, stream>>>(
      hA, nullptr, Wl2, Wr2, Ws2, nullptr, nullptr, ab, Zbuf, nullptr, N, 256, 0, 128);
  combine<128, 7, 128, 1, 1><<<2048, 256, 0, stream>>>(
      Zbuf, adj, offs, cnt, invc, bl2, bs2, hB, sums, N);
  bn_affine<<<1, 128, 0, stream>>>(sums, g2, be2, ab, 128, invN);

  // L3: Z = bn2(hB) @ [Wl3 | Wr3+Ws3]; combine -> hC (relu+stats)
  gemm_big<0, 1, 0><<<dim3(RB, 1), 256, 0, stream>>>(
      hB, nullptr, Wl3, Wr3, Ws3, nullptr, nullptr, ab, Zbuf, nullptr, N, 128, 0, 64);
  combine<64, 6, 64, 1, 1><<<2048, 256, 0, stream>>>(
      Zbuf, adj, offs, cnt, invc, bl3, bs3, hC, sums, N);
  bn_affine<<<1, 64, 0, stream>>>(sums, g3, be3, ab, 64, invN);

  // L4: Z = bn3(hC) @ [Wl4 | Wr4+Ws4]; combine -> d_out (no relu/stats)
  gemm_big<0, 1, 0><<<dim3(RB, 1), 256, 0, stream>>>(
      hC, nullptr, Wl4, Wr4, Ws4, nullptr, nullptr, ab, Zbuf, nullptr, N, 64, 0, 40);
  combine<64, 6, 40, 0, 0><<<2048, 256, 0, stream>>>(
      Zbuf, adj, offs, cnt, invc, bl4, bs4, (float*)d_out, nullptr, N);
}